// Round 1
// baseline (2998.180 us; speedup 1.0000x reference)
//
#include <hip/hip_runtime.h>

#define EPSV 1e-5f

__device__ __forceinline__ float fast_rcp(float x) { return __builtin_amdgcn_rcpf(x); }
__device__ __forceinline__ float sigm(float x) { return fast_rcp(1.0f + __expf(-x)); }
__device__ __forceinline__ float tanhfast(float x) {
    float e = __expf(2.0f * x);
    return 1.0f - 2.0f * fast_rcp(e + 1.0f);
}

// ---------------- pack w2 (32,64,7) -> w2t[(i*7+k)*32 + o] ----------------
__global__ void pack_w2_kernel(const float* __restrict__ w2, float* __restrict__ w2t) {
    int idx = blockIdx.x * 256 + threadIdx.x;
    if (idx < 14336) {
        int o = idx / 448;
        int r = idx % 448;   // i*7+k
        w2t[r * 32 + o] = w2[idx];
    }
}

// ---------------- CNN: one block per window (b,t) ----------------
__global__ __launch_bounds__(256) void cnn_kernel(
    const float* __restrict__ x,
    const float* __restrict__ w1, const float* __restrict__ b1,
    const float* __restrict__ g1, const float* __restrict__ be1,
    const float* __restrict__ m1, const float* __restrict__ v1,
    const float* __restrict__ b2,
    const float* __restrict__ g2, const float* __restrict__ be2,
    const float* __restrict__ m2, const float* __restrict__ v2,
    const float* __restrict__ w3, const float* __restrict__ b3,
    const float* __restrict__ g3, const float* __restrict__ be3,
    const float* __restrict__ m3, const float* __restrict__ v3,
    const float* __restrict__ w2t,
    float* __restrict__ feats)
{
    __shared__ float winh[64];        // window + conv1 halo (4 each side), slots [0..57]
    __shared__ float w1t[9 * 64];     // [k][o]
    __shared__ float w3t[160 * 16];   // [(i*5+k)][o]
    __shared__ float a1[64 * 56];     // [i][3+p], halo 3 each side
    __shared__ float a2[32 * 54];     // [i][2+p], halo 2 each side
    __shared__ float s1[64], t1[64], s2[32], t2[32], s3[16], t3[16];
    __shared__ float psum[16 * 16];

    const int tid = threadIdx.x;
    const int w = blockIdx.x;
    const int b = w >> 11;
    const int t = w & 2047;

    // ---- init ----
    for (int idx = tid; idx < 576; idx += 256) {
        int o = idx / 9, k = idx % 9;
        w1t[k * 64 + o] = w1[idx];
    }
    for (int idx = tid; idx < 2560; idx += 256) {
        int o = idx / 160, r = idx % 160;
        w3t[r * 16 + o] = w3[idx];
    }
    if (tid < 64) {
        float s = g1[tid] * rsqrtf(v1[tid] + EPSV);
        s1[tid] = s;
        t1[tid] = (b1[tid] - m1[tid]) * s + be1[tid];
    } else if (tid < 96) {
        int o = tid - 64;
        float s = g2[o] * rsqrtf(v2[o] + EPSV);
        s2[o] = s;
        t2[o] = (b2[o] - m2[o]) * s + be2[o];
    } else if (tid < 112) {
        int o = tid - 96;
        float s = g3[o] * rsqrtf(v3[o] + EPSV);
        s3[o] = s;
        t3[o] = (b3[o] - m3[o]) * s + be3[o];
    }
    if (tid < 64) {
        winh[tid] = 0.0f;
        float* r = &a1[tid * 56];
        r[0] = 0.f; r[1] = 0.f; r[2] = 0.f; r[53] = 0.f; r[54] = 0.f; r[55] = 0.f;
    }
    if (tid < 32) {
        float* r = &a2[tid * 54];
        r[0] = 0.f; r[1] = 0.f; r[52] = 0.f; r[53] = 0.f;
    }
    __syncthreads();   // winh zeros before the window overwrite below
    if (tid < 50) {
        int gi = t + tid - 49;
        winh[4 + tid] = (gi >= 0) ? x[b * 2048 + gi] : 0.0f;
    }
    __syncthreads();

    // ---- conv1: 64 o x 4 pgroups of 13 positions ----
    {
        int o = tid >> 2, pg = tid & 3;
        int p0 = pg * 13;
        float wv[9];
        #pragma unroll
        for (int k = 0; k < 9; ++k) wv[k] = w1t[k * 64 + o];
        float sc = s1[o], tc = t1[o];
        #pragma unroll
        for (int q = 0; q < 13; ++q) {
            int p = p0 + q;
            if (p < 50) {
                float acc = 0.0f;
                #pragma unroll
                for (int k = 0; k < 9; ++k) acc = fmaf(wv[k], winh[p + k], acc);
                a1[o * 56 + 3 + p] = fmaxf(acc * sc + tc, 0.0f);
            }
        }
    }
    __syncthreads();

    // ---- conv2: 32 o x 8 pgroups of 7 positions, K = 64*7 ----
    {
        int o = tid >> 3, pg = tid & 7;
        int p0 = pg * 7;
        float acc[7];
        #pragma unroll
        for (int q = 0; q < 7; ++q) acc[q] = 0.0f;
        for (int i = 0; i < 64; ++i) {
            float av[13];
            #pragma unroll
            for (int j = 0; j < 13; ++j) av[j] = a1[i * 56 + p0 + j];
            #pragma unroll
            for (int k = 0; k < 7; ++k) {
                float wv = w2t[(i * 7 + k) * 32 + o];
                #pragma unroll
                for (int q = 0; q < 7; ++q) acc[q] = fmaf(wv, av[q + k], acc[q]);
            }
        }
        float sc = s2[o], tc = t2[o];
        #pragma unroll
        for (int q = 0; q < 7; ++q) {
            int p = p0 + q;
            if (p < 50) a2[o * 54 + 2 + p] = fmaxf(acc[q] * sc + tc, 0.0f);
        }
    }
    __syncthreads();

    // ---- conv3 + bn3 + relu + partial mean: 16 o x 16 pgroups of 4 ----
    {
        int o = tid & 15, pg = tid >> 4;
        int p0 = pg * 4;
        float acc[4];
        #pragma unroll
        for (int q = 0; q < 4; ++q) acc[q] = 0.0f;
        for (int i = 0; i < 32; ++i) {
            float av[8];
            #pragma unroll
            for (int j = 0; j < 8; ++j) av[j] = a2[i * 54 + p0 + j];
            #pragma unroll
            for (int k = 0; k < 5; ++k) {
                float wv = w3t[(i * 5 + k) * 16 + o];
                #pragma unroll
                for (int q = 0; q < 4; ++q) acc[q] = fmaf(wv, av[q + k], acc[q]);
            }
        }
        float sc = s3[o], tc = t3[o];
        float ps = 0.0f;
        #pragma unroll
        for (int q = 0; q < 4; ++q) {
            int p = p0 + q;
            if (p < 50) ps += fmaxf(acc[q] * sc + tc, 0.0f);
        }
        psum[pg * 16 + o] = ps;
    }
    __syncthreads();

    if (tid < 16) {
        float s = 0.0f;
        #pragma unroll
        for (int pg = 0; pg < 16; ++pg) s += psum[pg * 16 + tid];
        feats[w * 16 + tid] = s * (1.0f / 50.0f);
    }
}

// ---------------- LSTM: 16 persistent blocks (one per batch), both layers pipelined ----------------
__global__ __launch_bounds__(512, 2) void lstm_kernel(
    const float* __restrict__ feats,
    const float* __restrict__ wih0, const float* __restrict__ whh0,
    const float* __restrict__ bih0, const float* __restrict__ bhh0,
    const float* __restrict__ wih1, const float* __restrict__ whh1,
    const float* __restrict__ bih1, const float* __restrict__ bhh1,
    float* __restrict__ h2out)
{
    __shared__ float h0[64];     // layer0 hidden (also layer1 input)
    __shared__ float h2[64];     // layer1 hidden
    __shared__ float act0[256];
    __shared__ float act1[256];

    const int tid = threadIdx.x;
    const int b = blockIdx.x;
    const int layer = tid >> 8;
    const int g = tid & 255;
    const bool is_tanh = (g >= 128) && (g < 192);

    float wh[64], wx[64];
    float bb;
    if (layer == 0) {
        #pragma unroll
        for (int k = 0; k < 64; ++k) wh[k] = whh0[g * 64 + k];
        #pragma unroll
        for (int c = 0; c < 16; ++c) wx[c] = wih0[g * 16 + c];
        bb = bih0[g] + bhh0[g];
    } else {
        #pragma unroll
        for (int k = 0; k < 64; ++k) wh[k] = whh1[g * 64 + k];
        #pragma unroll
        for (int k = 0; k < 64; ++k) wx[k] = wih1[g * 64 + k];
        bb = bih1[g] + bhh1[g];
    }

    if (tid < 64) { h0[tid] = 0.0f; h2[tid] = 0.0f; }

    const float* fbase = feats + b * 2048 * 16;
    float f[16];
    if (layer == 0) {
        #pragma unroll
        for (int c = 0; c < 16; ++c) f[c] = fbase[c];
    }
    float c_st = 0.0f;
    __syncthreads();

    for (int s = 0; s <= 2048; ++s) {
        if (layer == 0) {
            if (s < 2048) {
                float a0 = bb, a1v = 0.f, a2v = 0.f, a3v = 0.f;
                #pragma unroll
                for (int c = 0; c < 16; c += 4) {
                    a0  = fmaf(f[c],     wx[c],     a0);
                    a1v = fmaf(f[c + 1], wx[c + 1], a1v);
                    a2v = fmaf(f[c + 2], wx[c + 2], a2v);
                    a3v = fmaf(f[c + 3], wx[c + 3], a3v);
                }
                #pragma unroll
                for (int k = 0; k < 64; k += 4) {
                    a0  = fmaf(h0[k],     wh[k],     a0);
                    a1v = fmaf(h0[k + 1], wh[k + 1], a1v);
                    a2v = fmaf(h0[k + 2], wh[k + 2], a2v);
                    a3v = fmaf(h0[k + 3], wh[k + 3], a3v);
                }
                float pre = (a0 + a1v) + (a2v + a3v);
                act0[g] = is_tanh ? tanhfast(pre) : sigm(pre);
                if (s + 1 < 2048) {   // prefetch next step's feats (uniform -> scalar loads)
                    const float* fp = fbase + (s + 1) * 16;
                    #pragma unroll
                    for (int c = 0; c < 16; ++c) f[c] = fp[c];
                }
            }
        } else {
            if (s >= 1) {   // layer1 runs one step behind: processes step s-1
                float a0 = bb, a1v = 0.f, a2v = 0.f, a3v = 0.f;
                #pragma unroll
                for (int k = 0; k < 64; k += 4) {   // input = h1[s-1] (in h0[])
                    a0  = fmaf(h0[k],     wx[k],     a0);
                    a1v = fmaf(h0[k + 1], wx[k + 1], a1v);
                    a2v = fmaf(h0[k + 2], wx[k + 2], a2v);
                    a3v = fmaf(h0[k + 3], wx[k + 3], a3v);
                }
                #pragma unroll
                for (int k = 0; k < 64; k += 4) {   // recurrent = h2[s-2]
                    a0  = fmaf(h2[k],     wh[k],     a0);
                    a1v = fmaf(h2[k + 1], wh[k + 1], a1v);
                    a2v = fmaf(h2[k + 2], wh[k + 2], a2v);
                    a3v = fmaf(h2[k + 3], wh[k + 3], a3v);
                }
                float pre = (a0 + a1v) + (a2v + a3v);
                act1[g] = is_tanh ? tanhfast(pre) : sigm(pre);
            }
        }
        __syncthreads();   // A: gate activations visible; state reads done
        if (tid < 64 && s < 2048) {
            float ii = act0[tid], ff = act0[64 + tid], gg = act0[128 + tid], oo = act0[192 + tid];
            c_st = fmaf(ff, c_st, ii * gg);
            h0[tid] = oo * tanhfast(c_st);
        }
        if (tid >= 256 && tid < 320 && s >= 1) {
            int j = tid & 63;
            float ii = act1[j], ff = act1[64 + j], gg = act1[128 + j], oo = act1[192 + j];
            c_st = fmaf(ff, c_st, ii * gg);
            float h = oo * tanhfast(c_st);
            h2[j] = h;
            h2out[(b * 2048 + (s - 1)) * 64 + j] = h;
        }
        __syncthreads();   // B: new state visible for next iteration
    }
}

// ---------------- FC head ----------------
__global__ __launch_bounds__(256) void fc_kernel(
    const float* __restrict__ h2o,
    const float* __restrict__ fc1w, const float* __restrict__ fc1b,
    const float* __restrict__ fc2w, const float* __restrict__ fc2b,
    float* __restrict__ out)
{
    int r = blockIdx.x * 256 + threadIdx.x;   // 32768 rows
    float h[64];
    const float4* hp = (const float4*)(h2o + r * 64);
    #pragma unroll
    for (int i = 0; i < 16; ++i) {
        float4 v = hp[i];
        h[4 * i] = v.x; h[4 * i + 1] = v.y; h[4 * i + 2] = v.z; h[4 * i + 3] = v.w;
    }
    float l0 = fc2b[0], l1 = fc2b[1];
    #pragma unroll 4
    for (int j = 0; j < 32; ++j) {
        float z = fc1b[j];
        #pragma unroll
        for (int k = 0; k < 64; ++k) z = fmaf(h[k], fc1w[j * 64 + k], z);
        z = fmaxf(z, 0.0f);
        l0 = fmaf(z, fc2w[j], l0);
        l1 = fmaf(z, fc2w[32 + j], l1);
    }
    out[r * 2] = l0;
    out[r * 2 + 1] = l1;
}

extern "C" void kernel_launch(void* const* d_in, const int* in_sizes, int n_in,
                              void* d_out, int out_size, void* d_ws, size_t ws_size,
                              hipStream_t stream) {
    const float* x    = (const float*)d_in[0];
    const float* w1   = (const float*)d_in[1];
    const float* b1   = (const float*)d_in[2];
    const float* g1   = (const float*)d_in[3];
    const float* be1  = (const float*)d_in[4];
    const float* m1   = (const float*)d_in[5];
    const float* v1   = (const float*)d_in[6];
    const float* w2   = (const float*)d_in[7];
    const float* b2   = (const float*)d_in[8];
    const float* g2   = (const float*)d_in[9];
    const float* be2  = (const float*)d_in[10];
    const float* m2   = (const float*)d_in[11];
    const float* v2   = (const float*)d_in[12];
    const float* w3   = (const float*)d_in[13];
    const float* b3   = (const float*)d_in[14];
    const float* g3   = (const float*)d_in[15];
    const float* be3  = (const float*)d_in[16];
    const float* m3   = (const float*)d_in[17];
    const float* v3   = (const float*)d_in[18];
    const float* wih0 = (const float*)d_in[19];
    const float* whh0 = (const float*)d_in[20];
    const float* bih0 = (const float*)d_in[21];
    const float* bhh0 = (const float*)d_in[22];
    const float* wih1 = (const float*)d_in[23];
    const float* whh1 = (const float*)d_in[24];
    const float* bih1 = (const float*)d_in[25];
    const float* bhh1 = (const float*)d_in[26];
    const float* fc1w = (const float*)d_in[27];
    const float* fc1b = (const float*)d_in[28];
    const float* fc2w = (const float*)d_in[29];
    const float* fc2b = (const float*)d_in[30];
    float* out = (float*)d_out;

    float* ws    = (float*)d_ws;
    float* feats = ws;                           // 32768*16 floats (2 MB)
    float* h2o   = ws + 32768 * 16;              // 32768*64 floats (8 MB)
    float* w2t   = ws + 32768 * 16 + 32768 * 64; // 14336 floats

    hipLaunchKernelGGL(pack_w2_kernel, dim3(56), dim3(256), 0, stream, w2, w2t);
    hipLaunchKernelGGL(cnn_kernel, dim3(32768), dim3(256), 0, stream,
                       x, w1, b1, g1, be1, m1, v1, b2, g2, be2, m2, v2,
                       w3, b3, g3, be3, m3, v3, w2t, feats);
    hipLaunchKernelGGL(lstm_kernel, dim3(16), dim3(512), 0, stream,
                       feats, wih0, whh0, bih0, bhh0, wih1, whh1, bih1, bhh1, h2o);
    hipLaunchKernelGGL(fc_kernel, dim3(128), dim3(256), 0, stream,
                       h2o, fc1w, fc1b, fc2w, fc2b, out);
}